// Round 13
// baseline (109.684 us; speedup 1.0000x reference)
//
#include <hip/hip_runtime.h>
#include <math.h>

#define PI_F 3.14159265358979323846f

typedef __attribute__((ext_vector_type(8))) short bf16x8;   // 8 bf16 (4 VGPRs)
typedef __attribute__((ext_vector_type(4))) float f32x4;    // MFMA C/D

// Persistent device scratch (rewritten fully on every launch).
__device__ float g_sang[48];       // style angles [b][q] (tanh*pi applied)
__device__ float g_cb[64];         // out_proj_b + res_proj_b
// bf16 operand tables for the epilogue GEMMs:
__device__ __attribute__((aligned(16))) unsigned short g_Urb[64 * 64];  // [t][s]
__device__ __attribute__((aligned(16))) unsigned short g_Uib[64 * 64];  // [t][s]
__device__ __attribute__((aligned(16))) unsigned short g_Zwc[64 * 64];  // [c][t]
// MFMA B operand for the conv GEMM (R11 layout, proven):
// [ntile(5)][slab(18)][lane(64)][j(8)]
__device__ __attribute__((aligned(16))) unsigned short g_Bm[5 * 18 * 64 * 8];

__device__ inline unsigned short bf16rne(float f) {
    unsigned u = __float_as_uint(f);
    return (unsigned short)((u + 0x7FFFu + ((u >> 16) & 1u)) >> 16);
}

// ---------------------------------------------------------------------------
// Prep, 64-thread blocks (verbatim R12).
//   bid 0      : Zw (transposed bf16) + combined bias
//   bid 1      : style angles
//   bid 2..65  : circuit column s = bid-2 (wave butterfly via __shfl_xor)
//   bid 66..155: Bm build (5760 lane-entries, 64 per block)
__global__ __launch_bounds__(64) void k_prep(
        const float* __restrict__ style,
        const float* __restrict__ dw, const float* __restrict__ rw,
        const float* __restrict__ s2dw, const float* __restrict__ s2db,
        const float* __restrict__ qcnn, const float* __restrict__ meas,
        const float* __restrict__ outw, const float* __restrict__ outb,
        const float* __restrict__ resb) {
    int bid = blockIdx.x;
    int t = threadIdx.x;

    if (bid >= 66) {  // Bm build
        int entry = (bid - 66) * 64 + t;          // 0..5759
        int nt   = entry / 1152;
        int rem  = entry - nt * 1152;
        int slab = rem >> 6;
        int ln   = rem & 63;
        int m    = ln & 15, quad = ln >> 4;
        int n    = nt * 16 + m;
        int ij   = slab >> 1;
        int ch   = (slab & 1) * 32;
#pragma unroll
        for (int j = 0; j < 8; ++j) {
            int c = ch + quad * 8 + j;
            int ko = c * 9 + ij;
            float v = 0.f;
            if (n < 64)      v = rw[n * 576 + ko];
            else if (n < 70) v = dw[(n - 64) * 576 + ko];
            g_Bm[entry * 8 + j] = bf16rne(v);
        }
        return;
    }
    if (bid == 0) {  // Zw (store transposed bf16: [c][t]) + combined bias
        float zr[6];
#pragma unroll
        for (int q = 0; q < 6; ++q) zr[q] = ((t >> (5 - q)) & 1) ? -1.f : 1.f;
#pragma unroll 8
        for (int c = 0; c < 64; ++c) {
            float z = 0.f;
#pragma unroll
            for (int q = 0; q < 6; ++q) z += outw[c * 6 + q] * zr[q];
            g_Zwc[c * 64 + t] = bf16rne(z);   // row t of Zw -> column t of Zwc
        }
        g_cb[t] = outb[t] + resb[t];
        return;
    }
    if (bid == 1) {  // style angles [b][q]
        if (t < 48) {
            int bb = t / 6, q = t % 6;
            float a = s2db[q];
#pragma unroll 8
            for (int j = 0; j < 128; ++j) a += style[bb * 128 + j] * s2dw[q * 128 + j];
            g_sang[t] = tanhf(a) * PI_F;
        }
        return;
    }

    // Circuit column s: lane t holds amplitude of basis state t (wire q = bit 5-q).
    int s = bid - 2;
    float ar = (t == s) ? 1.f : 0.f;
    float ai = 0.f;

#pragma unroll
    for (int l = 0; l < 2; ++l) {
#pragma unroll
        for (int wq = 0; wq < 6; ++wq) {
            int mask = 1 << (5 - wq);
            bool hi = (t & mask) != 0;
            float th = qcnn[((l * 6 + wq) * 2 + 0) * 3];
            float sg, cg; sincosf(0.5f * th, &sg, &cg);
            float pr = __shfl_xor(ar, mask);
            float pi2 = __shfl_xor(ai, mask);
            ar = hi ? (sg * pr + cg * ar) : (cg * ar - sg * pr);
            ai = hi ? (sg * pi2 + cg * ai) : (cg * ai - sg * pi2);
            float ph = qcnn[((l * 6 + wq) * 2 + 1) * 3];
            float sz, cz; sincosf(0.5f * ph, &sz, &cz);
            float szz = hi ? sz : -sz;
            float nr = cz * ar - szz * ai;
            float ni = cz * ai + szz * ar;
            ar = nr; ai = ni;
        }
#pragma unroll
        for (int wq = 0; wq < 6; ++wq) {  // ring CNOTs
            int cm = 1 << (5 - wq);
            int tm = 1 << (5 - ((wq + 1) % 6));
            float pr = __shfl_xor(ar, tm);
            float pi2 = __shfl_xor(ai, tm);
            if (t & cm) { ar = pr; ai = pi2; }
        }
    }
#pragma unroll
    for (int wq = 0; wq < 6; ++wq) {  // U3 measurement basis
        int mask = 1 << (5 - wq);
        bool hi = (t & mask) != 0;
        float th = meas[wq * 3 + 0], ph = meas[wq * 3 + 1], lm = meas[wq * 3 + 2];
        float st2, ct; sincosf(0.5f * th, &st2, &ct);
        float sl, cl;  sincosf(lm, &sl, &cl);
        float sp, cp;  sincosf(ph, &sp, &cp);
        float spl, cpl; sincosf(ph + lm, &spl, &cpl);
        float u01r = -cl * st2, u01i = -sl * st2;
        float u10r =  cp * st2, u10i =  sp * st2;
        float u11r =  cpl * ct, u11i =  spl * ct;
        float pr = __shfl_xor(ar, mask);
        float pi2 = __shfl_xor(ai, mask);
        float nr, ni;
        if (hi) {
            nr = u10r * pr - u10i * pi2 + u11r * ar - u11i * ai;
            ni = u10r * pi2 + u10i * pr + u11r * ai + u11i * ar;
        } else {
            nr = ct * ar + u01r * pr - u01i * pi2;
            ni = ct * ai + u01r * pi2 + u01i * pr;
        }
        ar = nr; ai = ni;
    }
    g_Urb[t * 64 + s] = bf16rne(ar);
    g_Uib[t * 64 + s] = bf16rne(ai);
}

// ---------------------------------------------------------------------------
// Main: 1024 threads = 64 pixels (lane==w) x 16 waves.
// R12 structure with two latency cuts:
//   (1) staging uses float4 loads along w (12 dword loads -> 3 dwordx4);
//   (2) epilogue B-fragments (Urb/Uib/Zwc) prefetched into registers right
//       after the conv GEMM, so their global latency hides under the
//       convres/fact/psi barrier chain instead of serializing after it.
__global__ __launch_bounds__(1024, 4) void k_main(const float* __restrict__ x,
                                                  const float* __restrict__ dpb,
                                                  float* __restrict__ out) {
    __shared__ __attribute__((aligned(16))) float smem[13504];  // 54016 B
    unsigned*             xsu32 = (unsigned*)smem;
    unsigned short*       xsw   = (unsigned short*)smem;
    const unsigned short* xsu   = (const unsigned short*)smem;
    float*          convres = smem + 8320;                      // [pix][81]
    float*          fact    = smem;                             // [12][64]
    unsigned short* psi_bf  = (unsigned short*)(smem + 1024);   // [64][72]
    unsigned short* p_bf    = (unsigned short*)(smem + 3328);   // [64][72]

    int tid  = threadIdx.x;
    int lane = tid & 63;                 // pixel within block (== w)
    int wid  = __builtin_amdgcn_readfirstlane(tid >> 6);  // 0..15
    int m    = lane & 15;
    int quad = lane >> 4;

    int p = blockIdx.x * 64 + lane;      // pixel id: b*4096 + h*64 + w
    int b = p >> 12;
    int h = (p >> 6) & 63;
    int w = p & 63;
    const float* xb = x + (b << 18);

    // ---- stage x-tile as bf16: xs[row][wp][c] (ushort strides c:1, wp:72,
    // row:4752; halo cols wp=0,65). float4 loads along w (the fast axis).
    if (tid < 216) {  // zero halo: 3 rows x 2 cols x 36 uints
        int r3 = tid / 72, rest = tid % 72;
        int half = rest / 36, cp = rest % 36;
        xsu32[(r3 * 66 + half * 65) * 36 + cp] = 0u;
    }
#pragma unroll
    for (int k = 0; k < 3; ++k) {
        int flat = k * 1024 + tid;       // 0..3071 = 3 rows x 64 c x 16 wquads
        int row  = flat >> 10;
        int rem  = flat & 1023;
        int c    = rem >> 4;
        int w4   = (rem & 15) << 2;
        int hh   = h + row - 1;
        float4 v = make_float4(0.f, 0.f, 0.f, 0.f);
        if ((unsigned)hh < 64u)
            v = *(const float4*)(xb + (c << 12) + (hh << 6) + w4);
        int base = (row * 66 + w4 + 1) * 72 + c;
        xsw[base]       = bf16rne(v.x);
        xsw[base + 72]  = bf16rne(v.y);
        xsw[base + 144] = bf16rne(v.z);
        xsw[base + 216] = bf16rne(v.w);
    }
    __syncthreads();

    // ---- conv+angle MFMA GEMM (verbatim R11/R12)
    int mt0 = wid >> 2, nt0 = wid & 3;
    const unsigned short* a0base = xsu + (mt0 * 16 + m) * 72 + quad * 8;
    const unsigned short* b0base = g_Bm + ((nt0 * 18) * 64 + lane) * 8;
    f32x4 acc0 = {0.f, 0.f, 0.f, 0.f};
    f32x4 acc1 = {0.f, 0.f, 0.f, 0.f};
    if (wid < 4) {
        const unsigned short* a1base = xsu + (wid * 16 + m) * 72 + quad * 8;
        const unsigned short* b1base = g_Bm + ((4 * 18) * 64 + lane) * 8;
#pragma unroll
        for (int slab = 0; slab < 18; ++slab) {
            int ij = slab >> 1, i = ij / 3, j = ij - 3 * (ij / 3);
            int aoff = i * 4752 + j * 72 + (slab & 1) * 32;
            bf16x8 a0 = *(const bf16x8*)(a0base + aoff);
            bf16x8 b0 = *(const bf16x8*)(b0base + slab * 512);
            acc0 = __builtin_amdgcn_mfma_f32_16x16x32_bf16(a0, b0, acc0, 0, 0, 0);
            bf16x8 a1 = *(const bf16x8*)(a1base + aoff);
            bf16x8 b1 = *(const bf16x8*)(b1base + slab * 512);
            acc1 = __builtin_amdgcn_mfma_f32_16x16x32_bf16(a1, b1, acc1, 0, 0, 0);
        }
    } else {
#pragma unroll
        for (int slab = 0; slab < 18; ++slab) {
            int ij = slab >> 1, i = ij / 3, j = ij - 3 * (ij / 3);
            int aoff = i * 4752 + j * 72 + (slab & 1) * 32;
            bf16x8 a0 = *(const bf16x8*)(a0base + aoff);
            bf16x8 b0 = *(const bf16x8*)(b0base + slab * 512);
            acc0 = __builtin_amdgcn_mfma_f32_16x16x32_bf16(a0, b0, acc0, 0, 0, 0);
        }
    }

    // ---- prefetch epilogue B-fragments (wave-uniform, data-independent):
    // their global latency hides under the next three barriers.
    const unsigned short* urp = g_Urb + (nt0 * 16 + m) * 64 + quad * 8;
    const unsigned short* uip = g_Uib + (nt0 * 16 + m) * 64 + quad * 8;
    const unsigned short* zcp = g_Zwc + (nt0 * 16 + m) * 64 + quad * 8;
    bf16x8 urA = *(const bf16x8*)(urp);
    bf16x8 urB = *(const bf16x8*)(urp + 32);
    bf16x8 uiA = *(const bf16x8*)(uip);
    bf16x8 uiB = *(const bf16x8*)(uip + 32);
    bf16x8 zcA = *(const bf16x8*)(zcp);
    bf16x8 zcB = *(const bf16x8*)(zcp + 32);

    // C/D layout (verified): col = lane&15 (=n), row = quad*4 + reg (=pixel).
#pragma unroll
    for (int r = 0; r < 4; ++r) {
        convres[(mt0 * 16 + quad * 4 + r) * 81 + nt0 * 16 + m] = acc0[r];
    }
    if (wid < 4) {
#pragma unroll
        for (int r = 0; r < 4; ++r) {
            convres[(wid * 16 + quad * 4 + r) * 81 + 64 + m] = acc1[r];
        }
    }
    __syncthreads();

    // ---- factors: waves 0-5 compute sincos(theta_q/2) for all 64 pixels
    if (wid < 6) {
        int q = wid;
        float t = convres[lane * 81 + 64 + q];
        float theta = tanhf(t + dpb[q]) * PI_F + g_sang[b * 6 + q];
        float sv, cv; sincosf(0.5f * theta, &sv, &cv);
        fact[q * 64 + lane] = sv;
        fact[(6 + q) * 64 + lane] = cv;
    }
    __syncthreads();

    // ---- psi (bf16): each wave builds states 4*wid..4*wid+3 for its pixel
    {
        float f0s = fact[0 * 64 + lane], f0c = fact[6 * 64 + lane];
        float f1s = fact[1 * 64 + lane], f1c = fact[7 * 64 + lane];
        float f2s = fact[2 * 64 + lane], f2c = fact[8 * 64 + lane];
        float f3s = fact[3 * 64 + lane], f3c = fact[9 * 64 + lane];
        float f4s = fact[4 * 64 + lane], f4c = fact[10 * 64 + lane];
        float f5s = fact[5 * 64 + lane], f5c = fact[11 * 64 + lane];
        int sb = wid * 4;
        float pre = (((sb >> 5) & 1) ? f0s : f0c)
                  * (((sb >> 4) & 1) ? f1s : f1c)
                  * (((sb >> 3) & 1) ? f2s : f2c)
                  * (((sb >> 2) & 1) ? f3s : f3c);
        unsigned short pk[4];
#pragma unroll
        for (int ti = 0; ti < 4; ++ti) {
            float v = pre * ((ti & 2) ? f4s : f4c) * ((ti & 1) ? f5s : f5c);
            pk[ti] = bf16rne(v);
        }
        *(uint2*)(psi_bf + lane * 72 + sb) =
            make_uint2((unsigned)pk[0] | ((unsigned)pk[1] << 16),
                       (unsigned)pk[2] | ((unsigned)pk[3] << 16));
    }
    __syncthreads();

    // ---- GEMM 1/2: Yr/Yi[pix][t] = psi[pix][s] @ U[t][s]^T, tile (mt0,nt0)
    {
        const unsigned short* pa = psi_bf + (mt0 * 16 + m) * 72 + quad * 8;
        bf16x8 aA = *(const bf16x8*)(pa);
        bf16x8 aB = *(const bf16x8*)(pa + 32);
        f32x4 c1 = {0.f, 0.f, 0.f, 0.f};
        f32x4 c2 = {0.f, 0.f, 0.f, 0.f};
        c1 = __builtin_amdgcn_mfma_f32_16x16x32_bf16(aA, urA, c1, 0, 0, 0);
        c1 = __builtin_amdgcn_mfma_f32_16x16x32_bf16(aB, urB, c1, 0, 0, 0);
        c2 = __builtin_amdgcn_mfma_f32_16x16x32_bf16(aA, uiA, c2, 0, 0, 0);
        c2 = __builtin_amdgcn_mfma_f32_16x16x32_bf16(aB, uiB, c2, 0, 0, 0);
#pragma unroll
        for (int r = 0; r < 4; ++r) {
            float pv = c1[r] * c1[r] + c2[r] * c2[r];
            p_bf[(mt0 * 16 + quad * 4 + r) * 72 + nt0 * 16 + m] = bf16rne(pv);
        }
    }
    __syncthreads();

    // ---- GEMM 3: O[pix][c] = P[pix][t] @ Zw[t][c], accumulate into convres
    {
        const unsigned short* pa = p_bf + (mt0 * 16 + m) * 72 + quad * 8;
        f32x4 o = {0.f, 0.f, 0.f, 0.f};
        o = __builtin_amdgcn_mfma_f32_16x16x32_bf16(*(const bf16x8*)(pa), zcA, o, 0, 0, 0);
        o = __builtin_amdgcn_mfma_f32_16x16x32_bf16(*(const bf16x8*)(pa + 32), zcB, o, 0, 0, 0);
#pragma unroll
        for (int r = 0; r < 4; ++r) {
            convres[(mt0 * 16 + quad * 4 + r) * 81 + nt0 * 16 + m] += o[r];
        }
    }
    __syncthreads();

    // ---- coalesced store: each wave stores 4 channels for all 64 pixels
    int ob = (b << 18) + (h << 6) + w;
#pragma unroll
    for (int kk = 0; kk < 4; ++kk) {
        int c = wid * 4 + kk;
        out[ob + (c << 12)] = convres[lane * 81 + c] + g_cb[c];
    }
}

// ---------------------------------------------------------------------------
extern "C" void kernel_launch(void* const* d_in, const int* in_sizes, int n_in,
                              void* d_out, int out_size, void* d_ws, size_t ws_size,
                              hipStream_t stream) {
    const float* x     = (const float*)d_in[0];
    const float* style = (const float*)d_in[1];
    const float* dw    = (const float*)d_in[2];
    const float* dpb   = (const float*)d_in[3];
    const float* s2dw  = (const float*)d_in[4];
    const float* s2db  = (const float*)d_in[5];
    const float* qcnn  = (const float*)d_in[6];
    const float* meas  = (const float*)d_in[7];
    const float* outw  = (const float*)d_in[8];
    const float* outb  = (const float*)d_in[9];
    const float* rw    = (const float*)d_in[10];
    const float* resb  = (const float*)d_in[11];
    float* out = (float*)d_out;

    hipLaunchKernelGGL(k_prep, dim3(156), dim3(64), 0, stream,
                       style, dw, rw, s2dw, s2db, qcnn, meas, outw, outb, resb);
    hipLaunchKernelGGL(k_main, dim3(512), dim3(1024), 0, stream, x, dpb, out);
}